// Round 2
// baseline (574.506 us; speedup 1.0000x reference)
//
#include <hip/hip_runtime.h>
#include <stdint.h>

// Problem constants
#define DIMC   256
#define NHEADS 8
#define HD     32
#define BATCH  4
#define SEQ    2048
#define MTOT   (BATCH * SEQ)        // 8192 tokens
#define QKVN   (MTOT * DIMC)        // 2097152 elements per q/k/v tensor
#define SCALE  0.17677669529663687f // 1/sqrt(32)

// ---------------------------------------------------------------------------
// Generic GEMM: out(M x Nout) = A(M x 256) @ W(Nout x 256)^T + bias
// All fp32. fp32 accumulate.
// mode 0: scatter epilogue into q/k/v buffers laid out [3][B*H][SEQ][HD]
// mode 1: plain store, Nout == 256 (projection -> d_out)
// Tile: 64x64, BK=16, 256 threads, 4x4 micro-tile with stride-16 lanes.
// ---------------------------------------------------------------------------
__global__ __launch_bounds__(256) void gemm_bias_kernel(
    const float* __restrict__ A,
    const float* __restrict__ W,
    const float* __restrict__ bias,
    float* __restrict__ out,
    int mode)
{
    __shared__ float As[16][65];
    __shared__ float Bs[16][65];

    const int t  = threadIdx.x;
    const int tx = t & 15;
    const int ty = t >> 4;
    const int m0 = blockIdx.y * 64;
    const int n0 = blockIdx.x * 64;
    const int lrow = t >> 2;          // 0..63
    const int lk4  = (t & 3) << 2;    // 0,4,8,12

    float acc[4][4];
    #pragma unroll
    for (int i = 0; i < 4; i++)
        #pragma unroll
        for (int j = 0; j < 4; j++) acc[i][j] = 0.f;

    for (int k0 = 0; k0 < 256; k0 += 16) {
        __syncthreads();
        float4 av = *(const float4*)(A + (size_t)(m0 + lrow) * 256 + k0 + lk4);
        float4 wv = *(const float4*)(W + (size_t)(n0 + lrow) * 256 + k0 + lk4);
        As[lk4 + 0][lrow] = av.x;
        As[lk4 + 1][lrow] = av.y;
        As[lk4 + 2][lrow] = av.z;
        As[lk4 + 3][lrow] = av.w;
        Bs[lk4 + 0][lrow] = wv.x;
        Bs[lk4 + 1][lrow] = wv.y;
        Bs[lk4 + 2][lrow] = wv.z;
        Bs[lk4 + 3][lrow] = wv.w;
        __syncthreads();

        #pragma unroll
        for (int kk = 0; kk < 16; kk++) {
            float a[4], b[4];
            #pragma unroll
            for (int i = 0; i < 4; i++) a[i] = As[kk][ty + 16 * i];
            #pragma unroll
            for (int j = 0; j < 4; j++) b[j] = Bs[kk][tx + 16 * j];
            #pragma unroll
            for (int i = 0; i < 4; i++)
                #pragma unroll
                for (int j = 0; j < 4; j++)
                    acc[i][j] += a[i] * b[j];
        }
    }

    #pragma unroll
    for (int j = 0; j < 4; j++) {
        int n = n0 + tx + 16 * j;
        float bv = bias[n];
        #pragma unroll
        for (int i = 0; i < 4; i++) {
            int m = m0 + ty + 16 * i;
            float val = acc[i][j] + bv;
            if (mode == 0) {
                int which = n >> 8;         // 0..2  (q/k/v)
                int h     = (n >> 5) & 7;   // head
                int d     = n & 31;         // head dim
                int b_    = m >> 11;        // batch
                int nn    = m & 2047;       // seq pos
                out[(size_t)which * QKVN +
                    ((size_t)(b_ * NHEADS + h) * SEQ + nn) * HD + d] = val;
            } else {
                out[(size_t)m * 256 + n] = val;
            }
        }
    }
}

// ---------------------------------------------------------------------------
// Flash attention: one block per (b, h, 64-query tile); 256 threads.
// Online softmax over 64-key tiles. Bias is 7x7-periodic, shared across heads.
// Thread map: rg = t>>4 (16 row groups), cg = t&15.
//   scores:  rows {rg+16i}, cols {cg+16j}  (4x4 per thread)
//   PV/out:  rows {rg+16i}, dims {cg, cg+16} (4x2 per thread)
// ---------------------------------------------------------------------------
__global__ __launch_bounds__(256) void attn_kernel(
    const float* __restrict__ Q,   // [B*H][SEQ][HD]
    const float* __restrict__ K,
    const float* __restrict__ V,
    const float* __restrict__ table,
    float* __restrict__ AO)        // [B][SEQ][DIMC]
{
    __shared__ float qs[64][33];
    __shared__ float ks[64][33];
    __shared__ float vs[64][33];
    __shared__ float ps[64][65];
    __shared__ float bias7[7][7];

    const int t   = threadIdx.x;
    const int bid = blockIdx.x;
    const int qb  = bid & 31;        // SEQ/64 = 32 query tiles
    const int bh  = bid >> 5;        // 0..31
    const int b   = bh >> 3;
    const int h   = bh & 7;
    const int q0  = qb * 64;

    const float* Qg = Q + (size_t)bh * (SEQ * HD);
    const float* Kg = K + (size_t)bh * (SEQ * HD);
    const float* Vg = V + (size_t)bh * (SEQ * HD);

    if (t < 49) {
        int i = t / 7, j = t % 7;
        bias7[i][j] = table[i - j + 6];
    }
    {   // stage Q tile (64 x 32), 32B per thread
        int r = t >> 2, c0 = (t & 3) << 3;
        float4 u0 = *(const float4*)(Qg + (size_t)(q0 + r) * HD + c0);
        float4 u1 = *(const float4*)(Qg + (size_t)(q0 + r) * HD + c0 + 4);
        float* dst = &qs[r][c0];
        dst[0] = u0.x; dst[1] = u0.y; dst[2] = u0.z; dst[3] = u0.w;
        dst[4] = u1.x; dst[5] = u1.y; dst[6] = u1.z; dst[7] = u1.w;
    }

    const int rg = t >> 4, cg = t & 15;
    float m_i[4], l_i[4], acc[4][2];
    int qm7[4];
    #pragma unroll
    for (int i = 0; i < 4; i++) {
        m_i[i] = -1e30f; l_i[i] = 0.f;
        acc[i][0] = 0.f; acc[i][1] = 0.f;
        qm7[i] = (q0 + rg + 16 * i) % 7;
    }

    for (int j0 = 0; j0 < SEQ; j0 += 64) {
        __syncthreads();
        {   // stage K,V tiles (64 x 32 each)
            int r = t >> 2, c0 = (t & 3) << 3;
            float4 k0v = *(const float4*)(Kg + (size_t)(j0 + r) * HD + c0);
            float4 k1v = *(const float4*)(Kg + (size_t)(j0 + r) * HD + c0 + 4);
            float* dk = &ks[r][c0];
            dk[0] = k0v.x; dk[1] = k0v.y; dk[2] = k0v.z; dk[3] = k0v.w;
            dk[4] = k1v.x; dk[5] = k1v.y; dk[6] = k1v.z; dk[7] = k1v.w;
            float4 v0v = *(const float4*)(Vg + (size_t)(j0 + r) * HD + c0);
            float4 v1v = *(const float4*)(Vg + (size_t)(j0 + r) * HD + c0 + 4);
            float* dv = &vs[r][c0];
            dv[0] = v0v.x; dv[1] = v0v.y; dv[2] = v0v.z; dv[3] = v0v.w;
            dv[4] = v1v.x; dv[5] = v1v.y; dv[6] = v1v.z; dv[7] = v1v.w;
        }
        __syncthreads();

        // scores: 4x4 per thread, dot over 32 dims
        float s[4][4];
        #pragma unroll
        for (int i = 0; i < 4; i++)
            #pragma unroll
            for (int j = 0; j < 4; j++) s[i][j] = 0.f;

        #pragma unroll 8
        for (int kx = 0; kx < 32; kx++) {
            float qv[4], kv[4];
            #pragma unroll
            for (int i = 0; i < 4; i++) qv[i] = qs[rg + 16 * i][kx];
            #pragma unroll
            for (int j = 0; j < 4; j++) kv[j] = ks[cg + 16 * j][kx];
            #pragma unroll
            for (int i = 0; i < 4; i++)
                #pragma unroll
                for (int j = 0; j < 4; j++)
                    s[i][j] += qv[i] * kv[j];
        }

        int jm7[4];
        #pragma unroll
        for (int j = 0; j < 4; j++) jm7[j] = (j0 + cg + 16 * j) % 7;
        #pragma unroll
        for (int i = 0; i < 4; i++)
            #pragma unroll
            for (int j = 0; j < 4; j++)
                s[i][j] = s[i][j] * SCALE + bias7[qm7[i]][jm7[j]];

        // online softmax update (row owned by the 16 lanes sharing rg)
        #pragma unroll
        for (int i = 0; i < 4; i++) {
            float tmax = fmaxf(fmaxf(s[i][0], s[i][1]), fmaxf(s[i][2], s[i][3]));
            #pragma unroll
            for (int off = 1; off < 16; off <<= 1)
                tmax = fmaxf(tmax, __shfl_xor(tmax, off, 16));
            float mnew  = fmaxf(m_i[i], tmax);
            float alpha = __expf(m_i[i] - mnew);
            float rsum = 0.f;
            #pragma unroll
            for (int j = 0; j < 4; j++) {
                float p = __expf(s[i][j] - mnew);
                ps[rg + 16 * i][cg + 16 * j] = p;
                rsum += p;
            }
            #pragma unroll
            for (int off = 1; off < 16; off <<= 1)
                rsum += __shfl_xor(rsum, off, 16);
            l_i[i] = l_i[i] * alpha + rsum;
            m_i[i] = mnew;
            acc[i][0] *= alpha;
            acc[i][1] *= alpha;
        }
        __syncthreads();

        // PV: acc[i][dd] += sum_c p[row_i][c] * v[c][cg + 16*dd]
        #pragma unroll 8
        for (int c = 0; c < 64; c++) {
            float v0 = vs[c][cg];
            float v1 = vs[c][cg + 16];
            #pragma unroll
            for (int i = 0; i < 4; i++) {
                float p = ps[rg + 16 * i][c];
                acc[i][0] += p * v0;
                acc[i][1] += p * v1;
            }
        }
    }

    #pragma unroll
    for (int i = 0; i < 4; i++) {
        int qi = q0 + rg + 16 * i;
        float inv = 1.f / l_i[i];
        float* o = AO + ((size_t)(b * SEQ + qi)) * DIMC + h * HD;
        o[cg]      = acc[i][0] * inv;
        o[cg + 16] = acc[i][1] * inv;
    }
}

// ---------------------------------------------------------------------------
extern "C" void kernel_launch(void* const* d_in, const int* in_sizes, int n_in,
                              void* d_out, int out_size, void* d_ws, size_t ws_size,
                              hipStream_t stream) {
    const float* x      = (const float*)d_in[0]; // (4,2048,256)
    const float* qkv_w  = (const float*)d_in[1]; // (768,256)
    const float* qkv_b  = (const float*)d_in[2]; // (768)
    const float* proj_w = (const float*)d_in[3]; // (256,256)
    const float* proj_b = (const float*)d_in[4]; // (256)
    const float* table  = (const float*)d_in[5]; // (104)
    float* out = (float*)d_out;                  // (4,2048,256)

    float* ws = (float*)d_ws;
    float* qb = ws;                  // [B*H][SEQ][HD] fp32, 8 MB
    float* kb = ws + (size_t)QKVN;   // 8 MB
    float* vb = ws + (size_t)2 * QKVN;
    float* ao = ws + (size_t)3 * QKVN; // attention output (B,N,C) fp32, 8 MB

    // 1) QKV GEMM + bias, scatter into q/k/v
    gemm_bias_kernel<<<dim3(768 / 64, MTOT / 64), 256, 0, stream>>>(
        x, qkv_w, qkv_b, qb /* base: q at offset 0, kernel scatters */, 0);

    // 2) flash attention with periodic relative bias
    attn_kernel<<<dim3(BATCH * NHEADS * (SEQ / 64)), 256, 0, stream>>>(
        qb, kb, vb, table, ao);

    // 3) output projection
    gemm_bias_kernel<<<dim3(256 / 64, MTOT / 64), 256, 0, stream>>>(
        ao, proj_w, proj_b, out, 1);
}

// Round 3
// 185.670 us; speedup vs baseline: 3.0942x; 3.0942x over previous
//
#include <hip/hip_runtime.h>
#include <stdint.h>

// Problem constants
#define DIMC   256
#define NHEADS 8
#define HD     32
#define BATCH  4
#define SEQ    2048
#define MTOT   (BATCH * SEQ)        // 8192 tokens
#define QKVN   (MTOT * HD * NHEADS) // 2097152 elements per q/k/v tensor
#define SCALE  0.17677669529663687f // 1/sqrt(32)

typedef short    bf16x8 __attribute__((ext_vector_type(8)));
typedef float    f32x4  __attribute__((ext_vector_type(4)));

static __device__ __forceinline__ float bf2f(unsigned short u) {
    return __uint_as_float(((unsigned int)u) << 16);
}
static __device__ __forceinline__ unsigned short f2bf(float f) {
    unsigned int u = __float_as_uint(f);
    u += 0x7fffu + ((u >> 16) & 1u);   // RNE
    return (unsigned short)(u >> 16);
}

// ---------------------------------------------------------------------------
// MFMA GEMM: out(M x N) = A(M x 256) @ W(N x 256)^T + bias
// ABF16: A is bf16 (else fp32).  MODE 0: QKV scatter (q,k row-major; v
// transposed [bh][hd][seq]).  MODE 1: fp32 store to out.
// Block: 256 thr = 4 waves; tile 64x64; K-chunk 32; wave owns 16 rows.
// ---------------------------------------------------------------------------
template<bool ABF16, int MODE>
__global__ __launch_bounds__(256) void gemm_mfma_kernel(
    const void* __restrict__ Aptr,
    const float* __restrict__ W,
    const float* __restrict__ bias,
    unsigned short* __restrict__ qb,
    unsigned short* __restrict__ kb,
    unsigned short* __restrict__ vtb,
    float* __restrict__ outf)
{
    __shared__ unsigned short As[64][40];   // row stride 80B (16B aligned, 2-way banks)
    __shared__ unsigned short Ws[64][40];

    const int t    = threadIdx.x;
    const int wave = t >> 6;
    const int lane = t & 63;
    const int cg   = lane & 15;   // frag n / m index
    const int quad = lane >> 4;   // frag k-group
    const int m0   = blockIdx.y * 64;
    const int n0   = blockIdx.x * 64;
    const int r    = t >> 2;          // staging row 0..63
    const int c0   = (t & 3) << 3;    // staging k offset {0,8,16,24}

    f32x4 acc[4];
    #pragma unroll
    for (int c = 0; c < 4; c++) acc[c] = (f32x4){0.f, 0.f, 0.f, 0.f};

    for (int k0 = 0; k0 < 256; k0 += 32) {
        __syncthreads();
        if (ABF16) {
            const unsigned short* Ab = (const unsigned short*)Aptr;
            *(bf16x8*)&As[r][c0] =
                *(const bf16x8*)(Ab + (size_t)(m0 + r) * 256 + k0 + c0);
        } else {
            const float* Af = (const float*)Aptr;
            float4 a0 = *(const float4*)(Af + (size_t)(m0 + r) * 256 + k0 + c0);
            float4 a1 = *(const float4*)(Af + (size_t)(m0 + r) * 256 + k0 + c0 + 4);
            unsigned short tmp[8] = {f2bf(a0.x), f2bf(a0.y), f2bf(a0.z), f2bf(a0.w),
                                     f2bf(a1.x), f2bf(a1.y), f2bf(a1.z), f2bf(a1.w)};
            *(bf16x8*)&As[r][c0] = *(const bf16x8*)tmp;
        }
        {
            float4 w0 = *(const float4*)(W + (size_t)(n0 + r) * 256 + k0 + c0);
            float4 w1 = *(const float4*)(W + (size_t)(n0 + r) * 256 + k0 + c0 + 4);
            unsigned short tmp[8] = {f2bf(w0.x), f2bf(w0.y), f2bf(w0.z), f2bf(w0.w),
                                     f2bf(w1.x), f2bf(w1.y), f2bf(w1.z), f2bf(w1.w)};
            *(bf16x8*)&Ws[r][c0] = *(const bf16x8*)tmp;
        }
        __syncthreads();

        bf16x8 af = *(const bf16x8*)&As[wave * 16 + cg][quad * 8];
        bf16x8 wf[4];
        #pragma unroll
        for (int c = 0; c < 4; c++)
            wf[c] = *(const bf16x8*)&Ws[c * 16 + cg][quad * 8];
        #pragma unroll
        for (int c = 0; c < 4; c++)
            acc[c] = __builtin_amdgcn_mfma_f32_16x16x32_bf16(af, wf[c], acc[c], 0, 0, 0);
    }

    // epilogue: C/D layout col = cg, row = quad*4 + reg
    #pragma unroll
    for (int c = 0; c < 4; c++) {
        int n = n0 + c * 16 + cg;
        float bv = bias[n];
        #pragma unroll
        for (int rr = 0; rr < 4; rr++) {
            int m = m0 + wave * 16 + quad * 4 + rr;
            float val = acc[c][rr] + bv;
            if (MODE == 0) {
                int which = n >> 8;        // 0 q, 1 k, 2 v
                int h     = (n >> 5) & 7;
                int d     = n & 31;
                int b_    = m >> 11;
                int nn    = m & 2047;
                int bh    = b_ * NHEADS + h;
                if (which == 0)
                    qb[((size_t)bh * SEQ + nn) * HD + d] = f2bf(val);
                else if (which == 1)
                    kb[((size_t)bh * SEQ + nn) * HD + d] = f2bf(val);
                else
                    vtb[((size_t)bh * HD + d) * SEQ + nn] = f2bf(val);
            } else {
                outf[(size_t)m * 256 + n] = val;
            }
        }
    }
}

// ---------------------------------------------------------------------------
// MFMA flash attention. Block = 4 waves; each wave owns 16 query rows
// (barrier-free J-loop; P round-trips through a per-wave LDS region).
// Q,K: [bh][seq][32] bf16.  Vt: [bh][32][seq] bf16.  AO: [B*seq][256] bf16.
// ---------------------------------------------------------------------------
__global__ __launch_bounds__(256) void attn_mfma_kernel(
    const unsigned short* __restrict__ Q,
    const unsigned short* __restrict__ K,
    const unsigned short* __restrict__ Vt,
    const float* __restrict__ table,
    unsigned short* __restrict__ AO)
{
    __shared__ float bias7[7][8];
    __shared__ unsigned short Pbuf[4][16][72];  // per-wave; stride 144B kills conflicts

    const int t    = threadIdx.x;
    const int wave = t >> 6;
    const int lane = t & 63;
    const int cg   = lane & 15;
    const int quad = lane >> 4;

    const int bid = blockIdx.x;
    const int qb  = bid & 31;        // 2048/64 query tiles
    const int bh  = bid >> 5;
    const int b   = bh >> 3;
    const int h   = bh & 7;
    const int q0  = qb * 64 + wave * 16;   // this wave's query rows q0..q0+15

    if (t < 56) {
        int i = t >> 3, j = t & 7;
        bias7[i][j] = (j < 7) ? table[i - j + 6] : 0.f;
    }
    __syncthreads();

    const unsigned short* Kbase = K  + (size_t)bh * (SEQ * HD);
    const unsigned short* Vbase = Vt + (size_t)bh * (SEQ * HD);

    // Q A-fragment: A[m=cg][k=quad*8+j], kept in registers for all J-tiles
    bf16x8 qfrag = *(const bf16x8*)(Q + (size_t)bh * (SEQ * HD) +
                                    (size_t)(q0 + cg) * HD + quad * 8);

    f32x4 o0 = (f32x4){0.f, 0.f, 0.f, 0.f};
    f32x4 o1 = (f32x4){0.f, 0.f, 0.f, 0.f};
    float m_i[4], l_i[4];
    int qm7[4], jm7[4];
    #pragma unroll
    for (int rr = 0; rr < 4; rr++) {
        m_i[rr] = -1e30f; l_i[rr] = 0.f;
        qm7[rr] = (q0 + quad * 4 + rr) % 7;
        jm7[rr] = (rr * 16 + cg) % 7;       // rr doubles as jt here
    }

    for (int j0 = 0; j0 < SEQ; j0 += 64) {
        // K B-frags: B[k=quad*8+j][n=key cg] = K[j0+jt*16+cg][quad*8+j]
        bf16x8 kf[4];
        #pragma unroll
        for (int jt = 0; jt < 4; jt++)
            kf[jt] = *(const bf16x8*)(Kbase + (size_t)(j0 + jt * 16 + cg) * HD + quad * 8);
        // V B-frags: B[k=key][n=dim cg] = Vt[dt*16+cg][j0+kt*32+quad*8 ..]
        bf16x8 vf[2][2];
        #pragma unroll
        for (int kt = 0; kt < 2; kt++)
            #pragma unroll
            for (int dt = 0; dt < 2; dt++)
                vf[kt][dt] = *(const bf16x8*)(Vbase + (size_t)(dt * 16 + cg) * SEQ +
                                              j0 + kt * 32 + quad * 8);

        f32x4 s[4];
        #pragma unroll
        for (int jt = 0; jt < 4; jt++)
            s[jt] = __builtin_amdgcn_mfma_f32_16x16x32_bf16(
                qfrag, kf[jt], (f32x4){0.f, 0.f, 0.f, 0.f}, 0, 0, 0);

        // scale + periodic bias; sv[row reg][jt]
        float sv[4][4];
        #pragma unroll
        for (int rr = 0; rr < 4; rr++)
            #pragma unroll
            for (int jt = 0; jt < 4; jt++)
                sv[rr][jt] = s[jt][rr] * SCALE + bias7[qm7[rr]][jm7[jt]];
        #pragma unroll
        for (int jt = 0; jt < 4; jt++) {        // 64 ≡ 1 (mod 7)
            jm7[jt]++; if (jm7[jt] == 7) jm7[jt] = 0;
        }

        // online softmax per row (16 lanes of a quad share a row)
        unsigned short pb[4][4];
        float alpha[4];
        #pragma unroll
        for (int rr = 0; rr < 4; rr++) {
            float tm = fmaxf(fmaxf(sv[rr][0], sv[rr][1]), fmaxf(sv[rr][2], sv[rr][3]));
            #pragma unroll
            for (int off = 1; off < 16; off <<= 1)
                tm = fmaxf(tm, __shfl_xor(tm, off, 16));
            float mnew = fmaxf(m_i[rr], tm);
            alpha[rr]  = __expf(m_i[rr] - mnew);
            m_i[rr]    = mnew;
            float rs = 0.f;
            #pragma unroll
            for (int jt = 0; jt < 4; jt++) {
                float p = __expf(sv[rr][jt] - mnew);
                rs += p;
                pb[rr][jt] = f2bf(p);
            }
            #pragma unroll
            for (int off = 1; off < 16; off <<= 1)
                rs += __shfl_xor(rs, off, 16);
            l_i[rr] = l_i[rr] * alpha[rr] + rs;
        }
        #pragma unroll
        for (int rr = 0; rr < 4; rr++) { o0[rr] *= alpha[rr]; o1[rr] *= alpha[rr]; }

        // P -> per-wave LDS (C layout rows), then read back as A-frags
        #pragma unroll
        for (int rr = 0; rr < 4; rr++)
            #pragma unroll
            for (int jt = 0; jt < 4; jt++)
                Pbuf[wave][quad * 4 + rr][jt * 16 + cg] = pb[rr][jt];
        __builtin_amdgcn_s_waitcnt(0xC07F);   // lgkmcnt(0); same-wave RAW through LDS
        bf16x8 pa0 = *(const bf16x8*)&Pbuf[wave][cg][quad * 8];
        bf16x8 pa1 = *(const bf16x8*)&Pbuf[wave][cg][32 + quad * 8];

        o0 = __builtin_amdgcn_mfma_f32_16x16x32_bf16(pa0, vf[0][0], o0, 0, 0, 0);
        o0 = __builtin_amdgcn_mfma_f32_16x16x32_bf16(pa1, vf[1][0], o0, 0, 0, 0);
        o1 = __builtin_amdgcn_mfma_f32_16x16x32_bf16(pa0, vf[0][1], o1, 0, 0, 0);
        o1 = __builtin_amdgcn_mfma_f32_16x16x32_bf16(pa1, vf[1][1], o1, 0, 0, 0);
    }

    #pragma unroll
    for (int rr = 0; rr < 4; rr++) {
        float inv = 1.f / l_i[rr];
        size_t row = (size_t)b * SEQ + q0 + quad * 4 + rr;
        AO[row * DIMC + h * HD + cg]      = f2bf(o0[rr] * inv);
        AO[row * DIMC + h * HD + 16 + cg] = f2bf(o1[rr] * inv);
    }
}

// ---------------------------------------------------------------------------
extern "C" void kernel_launch(void* const* d_in, const int* in_sizes, int n_in,
                              void* d_out, int out_size, void* d_ws, size_t ws_size,
                              hipStream_t stream) {
    const float* x      = (const float*)d_in[0]; // (4,2048,256)
    const float* qkv_w  = (const float*)d_in[1]; // (768,256)
    const float* qkv_b  = (const float*)d_in[2]; // (768)
    const float* proj_w = (const float*)d_in[3]; // (256,256)
    const float* proj_b = (const float*)d_in[4]; // (256)
    const float* table  = (const float*)d_in[5]; // (104)
    float* out = (float*)d_out;                  // (4,2048,256) fp32

    unsigned short* ws  = (unsigned short*)d_ws;
    unsigned short* qb  = ws;                        // [bh][seq][32] bf16, 4 MB
    unsigned short* kb  = ws + (size_t)QKVN;         // 4 MB
    unsigned short* vtb = ws + (size_t)2 * QKVN;     // [bh][32][seq] bf16, 4 MB
    unsigned short* ao  = ws + (size_t)3 * QKVN;     // [B*seq][256] bf16, 4 MB

    // 1) QKV GEMM (fp32 in, bf16 MFMA, scatter epilogue; v transposed)
    gemm_mfma_kernel<false, 0><<<dim3(768 / 64, MTOT / 64), 256, 0, stream>>>(
        x, qkv_w, qkv_b, qb, kb, vtb, nullptr);

    // 2) MFMA flash attention with periodic relative bias
    attn_mfma_kernel<<<dim3(BATCH * NHEADS * (SEQ / 64)), 256, 0, stream>>>(
        qb, kb, vtb, table, ao);

    // 3) output projection (bf16 in, fp32 out)
    gemm_mfma_kernel<true, 1><<<dim3(256 / 64, MTOT / 64), 256, 0, stream>>>(
        ao, proj_w, proj_b, nullptr, nullptr, nullptr, out);
}

// Round 4
// 180.442 us; speedup vs baseline: 3.1839x; 1.0290x over previous
//
#include <hip/hip_runtime.h>
#include <stdint.h>

// Problem constants
#define DIMC   256
#define NHEADS 8
#define HD     32
#define BATCH  4
#define SEQ    2048
#define MTOT   (BATCH * SEQ)        // 8192 tokens
#define QKVN   (MTOT * HD * NHEADS) // 2097152 elements per q/k/v tensor
#define SCALE  0.17677669529663687f // 1/sqrt(32)
#define LOG2E  1.4426950408889634f
#define SCL2E  (SCALE * LOG2E)

typedef short bf16x8 __attribute__((ext_vector_type(8)));
typedef float f32x4  __attribute__((ext_vector_type(4)));

#if defined(__has_builtin)
#if __has_builtin(__builtin_amdgcn_exp2f)
#define EXP2F __builtin_amdgcn_exp2f
#else
#define EXP2F exp2f
#endif
#else
#define EXP2F exp2f
#endif

static __device__ __forceinline__ unsigned short f2bf(float f) {
    unsigned int u = __float_as_uint(f);
    u += 0x7fffu + ((u >> 16) & 1u);   // RNE
    return (unsigned short)(u >> 16);
}

// packed fp32x2 -> bf16x2 (single v_cvt_pk_bf16_f32 when available)
static __device__ __forceinline__ unsigned int cvt2(float a, float b) {
#if defined(__has_builtin) && __has_builtin(__builtin_amdgcn_cvt_pk_bf16_f32)
    typedef __bf16 bf2 __attribute__((ext_vector_type(2)));
    bf2 v = __builtin_amdgcn_cvt_pk_bf16_f32(a, b);
    return __builtin_bit_cast(unsigned int, v);
#else
    return (unsigned int)f2bf(a) | ((unsigned int)f2bf(b) << 16);
#endif
}

// ---------------------------------------------------------------------------
// MFMA GEMM: out(M x N) = A(M x 256) @ W(N x 256)^T + bias
// ABF16: A is bf16 (else fp32).  MODE 0: QKV scatter (q,k row-major; v
// transposed [bh][hd][seq]).  MODE 1: fp32 store to out.
// Block: 256 thr = 4 waves; tile 64x64; K-chunk 32; wave owns 16 rows.
// ---------------------------------------------------------------------------
template<bool ABF16, int MODE>
__global__ __launch_bounds__(256) void gemm_mfma_kernel(
    const void* __restrict__ Aptr,
    const float* __restrict__ W,
    const float* __restrict__ bias,
    unsigned short* __restrict__ qb,
    unsigned short* __restrict__ kb,
    unsigned short* __restrict__ vtb,
    float* __restrict__ outf)
{
    __shared__ unsigned short As[64][40];   // row stride 80B
    __shared__ unsigned short Ws[64][40];

    const int t    = threadIdx.x;
    const int wave = t >> 6;
    const int lane = t & 63;
    const int cg   = lane & 15;
    const int quad = lane >> 4;
    const int m0   = blockIdx.y * 64;
    const int n0   = blockIdx.x * 64;
    const int r    = t >> 2;          // staging row 0..63
    const int c0   = (t & 3) << 3;    // staging k offset {0,8,16,24}

    f32x4 acc[4];
    #pragma unroll
    for (int c = 0; c < 4; c++) acc[c] = (f32x4){0.f, 0.f, 0.f, 0.f};

    for (int k0 = 0; k0 < 256; k0 += 32) {
        __syncthreads();
        if (ABF16) {
            const unsigned short* Ab = (const unsigned short*)Aptr;
            *(bf16x8*)&As[r][c0] =
                *(const bf16x8*)(Ab + (size_t)(m0 + r) * 256 + k0 + c0);
        } else {
            const float* Af = (const float*)Aptr;
            float4 a0 = *(const float4*)(Af + (size_t)(m0 + r) * 256 + k0 + c0);
            float4 a1 = *(const float4*)(Af + (size_t)(m0 + r) * 256 + k0 + c0 + 4);
            uint4 pk;
            pk.x = cvt2(a0.x, a0.y); pk.y = cvt2(a0.z, a0.w);
            pk.z = cvt2(a1.x, a1.y); pk.w = cvt2(a1.z, a1.w);
            *(uint4*)&As[r][c0] = pk;
        }
        {
            float4 w0 = *(const float4*)(W + (size_t)(n0 + r) * 256 + k0 + c0);
            float4 w1 = *(const float4*)(W + (size_t)(n0 + r) * 256 + k0 + c0 + 4);
            uint4 pk;
            pk.x = cvt2(w0.x, w0.y); pk.y = cvt2(w0.z, w0.w);
            pk.z = cvt2(w1.x, w1.y); pk.w = cvt2(w1.z, w1.w);
            *(uint4*)&Ws[r][c0] = pk;
        }
        __syncthreads();

        bf16x8 af = *(const bf16x8*)&As[wave * 16 + cg][quad * 8];
        bf16x8 wf[4];
        #pragma unroll
        for (int c = 0; c < 4; c++)
            wf[c] = *(const bf16x8*)&Ws[c * 16 + cg][quad * 8];
        #pragma unroll
        for (int c = 0; c < 4; c++)
            acc[c] = __builtin_amdgcn_mfma_f32_16x16x32_bf16(af, wf[c], acc[c], 0, 0, 0);
    }

    // epilogue: C/D layout col = cg, row = quad*4 + reg
    #pragma unroll
    for (int c = 0; c < 4; c++) {
        int n = n0 + c * 16 + cg;
        float bv = bias[n];
        #pragma unroll
        for (int rr = 0; rr < 4; rr++) {
            int m = m0 + wave * 16 + quad * 4 + rr;
            float val = acc[c][rr] + bv;
            if (MODE == 0) {
                int which = n >> 8;        // 0 q, 1 k, 2 v
                int h     = (n >> 5) & 7;
                int d     = n & 31;
                int b_    = m >> 11;
                int nn    = m & 2047;
                int bh    = b_ * NHEADS + h;
                if (which == 0)
                    qb[((size_t)bh * SEQ + nn) * HD + d] = f2bf(val);
                else if (which == 1)
                    kb[((size_t)bh * SEQ + nn) * HD + d] = f2bf(val);
                else
                    vtb[((size_t)bh * HD + d) * SEQ + nn] = f2bf(val);
            } else {
                outf[(size_t)m * 256 + n] = val;
            }
        }
    }
}

// ---------------------------------------------------------------------------
// MFMA flash attention, S^T formulation, fixed-max softmax (m=0), deferred
// row-sum. Block = 4 waves; wave owns 16 query rows; barrier-free J-loop.
// Q,K: [bh][seq][32] bf16.  Vt: [bh][32][seq] bf16.  AO: [B*seq][256] bf16.
// Lane (cg,quad) score view: one query (cg), keys quad*4+rr+16*jt.
// ---------------------------------------------------------------------------
__global__ __launch_bounds__(256) void attn_mfma_kernel(
    const unsigned short* __restrict__ Q,
    const unsigned short* __restrict__ K,
    const unsigned short* __restrict__ Vt,
    const float* __restrict__ table,
    unsigned short* __restrict__ AO)
{
    __shared__ float Brow2[7][7][4];            // [q%7][kbase%7][rr] * LOG2E
    __shared__ unsigned short PL[4][16][72];    // per-wave P, row stride 144B

    const int t    = threadIdx.x;
    const int wave = t >> 6;
    const int lane = t & 63;
    const int cg   = lane & 15;
    const int quad = lane >> 4;

    const int bid = blockIdx.x;
    const int qb  = bid & 31;        // 2048/64 query tiles
    const int bh  = bid >> 5;
    const int b   = bh >> 3;
    const int h   = bh & 7;
    const int q0w = qb * 64 + wave * 16;   // this wave's 16 query rows

    if (t < 196) {
        int a = t / 28, rem = t % 28, k = rem / 4, rr = rem & 3;
        Brow2[a][k][rr] = table[a - ((k + rr) % 7) + 6] * LOG2E;
    }
    __syncthreads();

    const unsigned short* Kbase = K  + (size_t)bh * (SEQ * HD);
    const unsigned short* Vbase = Vt + (size_t)bh * (SEQ * HD);

    // Q B-fragment: B[k=quad*8+j][n=cg] = Q[q0w+cg][quad*8+j]
    bf16x8 qfrag = *(const bf16x8*)(Q + (size_t)bh * (SEQ * HD) +
                                    (size_t)(q0w + cg) * HD + quad * 8);

    const int qm7 = (q0w + cg) % 7;
    int kb7[4];
    #pragma unroll
    for (int jt = 0; jt < 4; jt++) kb7[jt] = (jt * 16 + quad * 4) % 7;

    f32x4 o0 = (f32x4){0.f, 0.f, 0.f, 0.f};
    f32x4 o1 = (f32x4){0.f, 0.f, 0.f, 0.f};
    float rs = 0.f;   // per-lane partial sum of exp(scores) for query cg

    for (int j0 = 0; j0 < SEQ; j0 += 64) {
        // K A-frags: A[m=cg][k=quad*8+j] = K[j0+jt*16+cg][quad*8+j]
        bf16x8 kf[4];
        #pragma unroll
        for (int jt = 0; jt < 4; jt++)
            kf[jt] = *(const bf16x8*)(Kbase + (size_t)(j0 + jt * 16 + cg) * HD + quad * 8);
        // V B-frags: B[k=key][n=dim cg] = Vt[dt*16+cg][j0+kt*32+quad*8+..]
        bf16x8 vf[2][2];
        #pragma unroll
        for (int kt = 0; kt < 2; kt++)
            #pragma unroll
            for (int dt = 0; dt < 2; dt++)
                vf[kt][dt] = *(const bf16x8*)(Vbase + (size_t)(dt * 16 + cg) * SEQ +
                                              j0 + kt * 32 + quad * 8);

        // S^T tiles: D[m=key][n=query]
        f32x4 s[4];
        #pragma unroll
        for (int jt = 0; jt < 4; jt++)
            s[jt] = __builtin_amdgcn_mfma_f32_16x16x32_bf16(
                kf[jt], qfrag, (f32x4){0.f, 0.f, 0.f, 0.f}, 0, 0, 0);

        // p = exp2(s*SCALE*log2e + bias*log2e); write P[query][key] to LDS
        #pragma unroll
        for (int jt = 0; jt < 4; jt++) {
            float4 bb = *(const float4*)&Brow2[qm7][kb7[jt]][0];
            float p0 = EXP2F(s[jt][0] * SCL2E + bb.x);
            float p1 = EXP2F(s[jt][1] * SCL2E + bb.y);
            float p2 = EXP2F(s[jt][2] * SCL2E + bb.z);
            float p3 = EXP2F(s[jt][3] * SCL2E + bb.w);
            rs += (p0 + p1) + (p2 + p3);
            uint2 w;
            w.x = cvt2(p0, p1);
            w.y = cvt2(p2, p3);
            *(uint2*)&PL[wave][cg][jt * 16 + quad * 4] = w;
            kb7[jt] = (kb7[jt] == 6) ? 0 : kb7[jt] + 1;   // j0 += 64 ≡ +1 (mod 7)
        }
        __builtin_amdgcn_s_waitcnt(0xC07F);   // lgkmcnt(0): wave-local LDS RAW

        // P A-frags: A[m=query cg][k=key quad*8+j]
        bf16x8 pa0 = *(const bf16x8*)&PL[wave][cg][quad * 8];
        bf16x8 pa1 = *(const bf16x8*)&PL[wave][cg][32 + quad * 8];

        o0 = __builtin_amdgcn_mfma_f32_16x16x32_bf16(pa0, vf[0][0], o0, 0, 0, 0);
        o0 = __builtin_amdgcn_mfma_f32_16x16x32_bf16(pa1, vf[1][0], o0, 0, 0, 0);
        o1 = __builtin_amdgcn_mfma_f32_16x16x32_bf16(pa0, vf[0][1], o1, 0, 0, 0);
        o1 = __builtin_amdgcn_mfma_f32_16x16x32_bf16(pa1, vf[1][1], o1, 0, 0, 0);
    }

    // row sums: reduce over the 4 quads holding query cg
    rs += __shfl_xor(rs, 16, 64);
    rs += __shfl_xor(rs, 32, 64);

    #pragma unroll
    for (int rr = 0; rr < 4; rr++) {
        float lr  = __shfl(rs, quad * 4 + rr, 16);  // l for query quad*4+rr
        float inv = 1.f / lr;
        size_t row = (size_t)b * SEQ + q0w + quad * 4 + rr;
        AO[row * DIMC + h * HD + cg]      = f2bf(o0[rr] * inv);
        AO[row * DIMC + h * HD + 16 + cg] = f2bf(o1[rr] * inv);
    }
}

// ---------------------------------------------------------------------------
extern "C" void kernel_launch(void* const* d_in, const int* in_sizes, int n_in,
                              void* d_out, int out_size, void* d_ws, size_t ws_size,
                              hipStream_t stream) {
    const float* x      = (const float*)d_in[0]; // (4,2048,256)
    const float* qkv_w  = (const float*)d_in[1]; // (768,256)
    const float* qkv_b  = (const float*)d_in[2]; // (768)
    const float* proj_w = (const float*)d_in[3]; // (256,256)
    const float* proj_b = (const float*)d_in[4]; // (256)
    const float* table  = (const float*)d_in[5]; // (104)
    float* out = (float*)d_out;                  // (4,2048,256) fp32

    unsigned short* ws  = (unsigned short*)d_ws;
    unsigned short* qb  = ws;                        // [bh][seq][32] bf16, 4 MB
    unsigned short* kb  = ws + (size_t)QKVN;         // 4 MB
    unsigned short* vtb = ws + (size_t)2 * QKVN;     // [bh][32][seq] bf16, 4 MB
    unsigned short* ao  = ws + (size_t)3 * QKVN;     // [B*seq][256] bf16, 4 MB

    // 1) QKV GEMM (fp32 in, bf16 MFMA, scatter epilogue; v transposed)
    gemm_mfma_kernel<false, 0><<<dim3(768 / 64, MTOT / 64), 256, 0, stream>>>(
        x, qkv_w, qkv_b, qb, kb, vtb, nullptr);

    // 2) MFMA flash attention with periodic relative bias
    attn_mfma_kernel<<<dim3(BATCH * NHEADS * (SEQ / 64)), 256, 0, stream>>>(
        qb, kb, vtb, table, ao);

    // 3) output projection (bf16 in, fp32 out)
    gemm_mfma_kernel<true, 1><<<dim3(256 / 64, MTOT / 64), 256, 0, stream>>>(
        ao, proj_w, proj_b, nullptr, nullptr, nullptr, out);
}